// Round 1
// baseline (616.829 us; speedup 1.0000x reference)
//
#include <hip/hip_runtime.h>
#include <hip/hip_bf16.h>
#include <math.h>

#define NP 100000
#define KC 64
#define OD 1024
#define EPSF 1e-6f

#define ROWS_PER_BLOCK 128
#define NBLOCKS ((NP + ROWS_PER_BLOCK - 1) / ROWS_PER_BLOCK)  // 782

typedef __attribute__((ext_vector_type(8))) short short8;
typedef __attribute__((ext_vector_type(4))) float f32x4;

// ---- ws layout ----
// [0      .. 256)   : logw, 64 floats
// [256    .. 6512)  : per-block double partials (NBLOCKS * 8)
// [8192   .. +128K) : B_hi  (KC*OD bf16, community-major = B^T frag layout)
// [139264 .. +128K) : B_lo
#define WS_LOGW      0
#define WS_PARTIALS  256
#define WS_BHI       8192
#define WS_BLO       (8192 + KC * OD * 2)

__device__ __forceinline__ unsigned short f32_bf16_rn(float f) {
  unsigned int u = __float_as_uint(f);
  unsigned int r = u + 0x7fffu + ((u >> 16) & 1u);
  return (unsigned short)(r >> 16);
}

__global__ void prep_kernel(const float* __restrict__ otu,
                            const float* __restrict__ comm,
                            unsigned short* __restrict__ bhi,
                            unsigned short* __restrict__ blo,
                            float* __restrict__ logw) {
  int b = blockIdx.x;
  if (b < KC) {
    const float* src = otu + b * OD;
    for (int o = threadIdx.x; o < OD; o += blockDim.x) {
      float x = logf(src[o] + EPSF);
      unsigned short h = f32_bf16_rn(x);
      float hf = __uint_as_float(((unsigned int)h) << 16);
      unsigned short l = f32_bf16_rn(x - hf);
      bhi[b * OD + o] = h;
      blo[b * OD + o] = l;
    }
  } else {
    if (threadIdx.x < KC) logw[threadIdx.x] = logf(comm[threadIdx.x] + EPSF);
  }
}

// Main kernel: 4 waves * 32 rows = 128 particle rows per block, all 64 community
// cols per wave. mfma_f32_16x16x32_bf16; A (counts) loaded fp32 from global in
// frag layout and truncated to bf16 (exact: counts are small integers).
__global__ __launch_bounds__(256, 3)
void ll_kernel(const float* __restrict__ counts,
               const unsigned short* __restrict__ bhi,
               const unsigned short* __restrict__ blo,
               const float* __restrict__ logw,
               double* __restrict__ partials) {
  const int tid = threadIdx.x;
  const int wave = tid >> 6;
  const int lane = tid & 63;
  const int g = lane >> 4;   // k-group within frag
  const int c = lane & 15;   // A-row / B-col within 16-tile
  const int rowBase = blockIdx.x * ROWS_PER_BLOCK + wave * 32;

  f32x4 acc[2][4];
#pragma unroll
  for (int i = 0; i < 2; ++i)
#pragma unroll
    for (int j = 0; j < 4; ++j)
      acc[i][j] = (f32x4){0.f, 0.f, 0.f, 0.f};

  int r0 = rowBase + c;      if (r0 >= NP) r0 = NP - 1;  // clamp (tail rows dropped in epilogue)
  int r1 = rowBase + 16 + c; if (r1 >= NP) r1 = NP - 1;
  const float* pa0 = counts + (size_t)r0 * OD + g * 8;
  const float* pa1 = counts + (size_t)r1 * OD + g * 8;
  const unsigned short* pbh = bhi + (size_t)c * OD + g * 8;
  const unsigned short* pbl = blo + (size_t)c * OD + g * 8;

  for (int ko = 0; ko < OD; ko += 32) {
    float4 a0lo = *(const float4*)(pa0 + ko);
    float4 a0hi = *(const float4*)(pa0 + ko + 4);
    float4 a1lo = *(const float4*)(pa1 + ko);
    float4 a1hi = *(const float4*)(pa1 + ko + 4);

    short8 fbh[4], fbl[4];
#pragma unroll
    for (int ct = 0; ct < 4; ++ct) {
      fbh[ct] = *(const short8*)(pbh + (size_t)(ct * 16) * OD + ko);
      fbl[ct] = *(const short8*)(pbl + (size_t)(ct * 16) * OD + ko);
    }

    // fp32 -> bf16 truncation, packed pairwise via v_perm (exact for integer counts)
    union { unsigned int u[4]; short8 v; } ua0, ua1;
    ua0.u[0] = __builtin_amdgcn_perm(__float_as_uint(a0lo.y), __float_as_uint(a0lo.x), 0x07060302u);
    ua0.u[1] = __builtin_amdgcn_perm(__float_as_uint(a0lo.w), __float_as_uint(a0lo.z), 0x07060302u);
    ua0.u[2] = __builtin_amdgcn_perm(__float_as_uint(a0hi.y), __float_as_uint(a0hi.x), 0x07060302u);
    ua0.u[3] = __builtin_amdgcn_perm(__float_as_uint(a0hi.w), __float_as_uint(a0hi.z), 0x07060302u);
    ua1.u[0] = __builtin_amdgcn_perm(__float_as_uint(a1lo.y), __float_as_uint(a1lo.x), 0x07060302u);
    ua1.u[1] = __builtin_amdgcn_perm(__float_as_uint(a1lo.w), __float_as_uint(a1lo.z), 0x07060302u);
    ua1.u[2] = __builtin_amdgcn_perm(__float_as_uint(a1hi.y), __float_as_uint(a1hi.x), 0x07060302u);
    ua1.u[3] = __builtin_amdgcn_perm(__float_as_uint(a1hi.w), __float_as_uint(a1hi.z), 0x07060302u);

#pragma unroll
    for (int ct = 0; ct < 4; ++ct) {
      acc[0][ct] = __builtin_amdgcn_mfma_f32_16x16x32_bf16(ua0.v, fbh[ct], acc[0][ct], 0, 0, 0);
      acc[1][ct] = __builtin_amdgcn_mfma_f32_16x16x32_bf16(ua1.v, fbh[ct], acc[1][ct], 0, 0, 0);
      acc[0][ct] = __builtin_amdgcn_mfma_f32_16x16x32_bf16(ua0.v, fbl[ct], acc[0][ct], 0, 0, 0);
      acc[1][ct] = __builtin_amdgcn_mfma_f32_16x16x32_bf16(ua1.v, fbl[ct], acc[1][ct], 0, 0, 0);
    }
  }

  // epilogue: + logw, logsumexp over 64 cols per row, accumulate rows
  float lw[4];
#pragma unroll
  for (int ct = 0; ct < 4; ++ct) lw[ct] = logw[ct * 16 + c];

  double lsum = 0.0;
#pragma unroll
  for (int rt = 0; rt < 2; ++rt) {
#pragma unroll
    for (int r = 0; r < 4; ++r) {
      // lane holds cols {ct*16+c}, row = rowBase + rt*16 + g*4 + r
      float v0 = acc[rt][0][r] + lw[0];
      float v1 = acc[rt][1][r] + lw[1];
      float v2 = acc[rt][2][r] + lw[2];
      float v3 = acc[rt][3][r] + lw[3];
      float m = fmaxf(fmaxf(v0, v1), fmaxf(v2, v3));
      m = fmaxf(m, __shfl_xor(m, 1));
      m = fmaxf(m, __shfl_xor(m, 2));
      m = fmaxf(m, __shfl_xor(m, 4));
      m = fmaxf(m, __shfl_xor(m, 8));
      float s = __expf(v0 - m) + __expf(v1 - m) + __expf(v2 - m) + __expf(v3 - m);
      s += __shfl_xor(s, 1);
      s += __shfl_xor(s, 2);
      s += __shfl_xor(s, 4);
      s += __shfl_xor(s, 8);
      float lse = m + __logf(s);
      int row = rowBase + rt * 16 + g * 4 + r;
      if (c == 0 && row < NP) lsum += (double)lse;
    }
  }
  lsum += __shfl_xor(lsum, 16);
  lsum += __shfl_xor(lsum, 32);

  __shared__ double wpart[4];
  if (lane == 0) wpart[wave] = lsum;
  __syncthreads();
  if (tid == 0) partials[blockIdx.x] = wpart[0] + wpart[1] + wpart[2] + wpart[3];
}

__global__ void finalize_kernel(const double* __restrict__ partials,
                                float* __restrict__ out) {
  double s = 0.0;
  for (int i = threadIdx.x; i < NBLOCKS; i += 256) s += partials[i];
  s += __shfl_xor(s, 1);
  s += __shfl_xor(s, 2);
  s += __shfl_xor(s, 4);
  s += __shfl_xor(s, 8);
  s += __shfl_xor(s, 16);
  s += __shfl_xor(s, 32);
  __shared__ double sp[4];
  int w = threadIdx.x >> 6, lane = threadIdx.x & 63;
  if (lane == 0) sp[w] = s;
  __syncthreads();
  if (threadIdx.x == 0) out[0] = (float)(sp[0] + sp[1] + sp[2] + sp[3]);
}

extern "C" void kernel_launch(void* const* d_in, const int* in_sizes, int n_in,
                              void* d_out, int out_size, void* d_ws, size_t ws_size,
                              hipStream_t stream) {
  const float* counts = (const float*)d_in[0];
  const float* otu    = (const float*)d_in[1];
  const float* comm   = (const float*)d_in[2];
  float* out = (float*)d_out;
  char* ws = (char*)d_ws;

  float* logw            = (float*)(ws + WS_LOGW);
  double* partials       = (double*)(ws + WS_PARTIALS);
  unsigned short* bhi    = (unsigned short*)(ws + WS_BHI);
  unsigned short* blo    = (unsigned short*)(ws + WS_BLO);

  prep_kernel<<<KC + 1, 256, 0, stream>>>(otu, comm, bhi, blo, logw);
  ll_kernel<<<NBLOCKS, 256, 0, stream>>>(counts, bhi, blo, logw, partials);
  finalize_kernel<<<1, 256, 0, stream>>>(partials, out);
}

// Round 2
// 571.801 us; speedup vs baseline: 1.0787x; 1.0787x over previous
//
#include <hip/hip_runtime.h>
#include <hip/hip_bf16.h>
#include <math.h>

#define NP 100000
#define KC 64
#define OD 1024
#define EPSF 1e-6f

#define ROWS_PER_BLOCK 128
#define NBLOCKS ((NP + ROWS_PER_BLOCK - 1) / ROWS_PER_BLOCK)  // 782
#define NT 32   // number of 32-wide k-steps

typedef __attribute__((ext_vector_type(8))) short short8;
typedef __attribute__((ext_vector_type(4))) float f32x4;

// ---- ws layout ----
// [0      .. 256)    : logw, 64 floats
// [256    .. 6512)   : per-block double partials (NBLOCKS * 8)
// [8192   .. +256K)  : staged B, 32 blocks of 8 KB. Within block t (byte offs):
//                      part(hi=0/lo=4096) + ct*1024 + lane*16,  lane = g*16 + c
//                      shorts: bf16 of log(otu[ct*16+c][t*32+g*8+kk]+eps), kk=0..7
#define WS_LOGW      0
#define WS_PARTIALS  256
#define WS_BSTAGE    8192

__device__ __forceinline__ unsigned short f32_bf16_rn(float f) {
  unsigned int u = __float_as_uint(f);
  unsigned int r = u + 0x7fffu + ((u >> 16) & 1u);
  return (unsigned short)(r >> 16);
}

__device__ __forceinline__ void gll16(const void* gsrc, void* lds) {
  __builtin_amdgcn_global_load_lds(
      (const __attribute__((address_space(1))) unsigned int*)gsrc,
      (__attribute__((address_space(3))) unsigned int*)lds, 16, 0, 0);
}

__global__ void prep_kernel(const float* __restrict__ otu,
                            const float* __restrict__ comm,
                            unsigned short* __restrict__ bstage,
                            float* __restrict__ logw) {
  int b = blockIdx.x;
  if (b < KC) {
    int c = b & 15, ct = b >> 4;
    for (int k = threadIdx.x; k < OD; k += blockDim.x) {
      float x = logf(otu[b * OD + k] + EPSF);
      unsigned short h = f32_bf16_rn(x);
      float hf = __uint_as_float(((unsigned int)h) << 16);
      unsigned short l = f32_bf16_rn(x - hf);
      int t = k >> 5, g = (k >> 3) & 3, kk = k & 7;
      // short-index within staged array
      size_t base = (size_t)t * 4096 + (size_t)ct * 512 + (size_t)(g * 16 + c) * 8 + kk;
      bstage[base] = h;           // hi half (bytes [0,4096) of the 8 KB block)
      bstage[base + 2048] = l;    // lo half
    }
  } else {
    if (threadIdx.x < KC) logw[threadIdx.x] = logf(comm[threadIdx.x] + EPSF);
  }
}

// 4 waves * 32 rows = 128 particle rows per block, all 64 community cols/wave.
// B double-buffered in LDS (frag-order, lane-linear => conflict-free), A
// register-prefetched one k-step ahead; counted vmcnt(4) + raw s_barrier keeps
// the A loads in flight across the barrier.
__global__ __launch_bounds__(256, 3)
void ll_kernel(const float* __restrict__ counts,
               const unsigned short* __restrict__ bstage,
               const float* __restrict__ logw,
               double* __restrict__ partials) {
  __shared__ unsigned short bufB[2][4096];  // 2 x 8 KB

  const int tid = threadIdx.x;
  const int wave = tid >> 6;
  const int lane = tid & 63;
  const int g = lane >> 4;   // k-group within frag
  const int c = lane & 15;   // A-row / B-col within 16-tile
  const int rowBase = blockIdx.x * ROWS_PER_BLOCK + wave * 32;

  f32x4 acc[2][4];
#pragma unroll
  for (int i = 0; i < 2; ++i)
#pragma unroll
    for (int j = 0; j < 4; ++j)
      acc[i][j] = (f32x4){0.f, 0.f, 0.f, 0.f};

  int r0 = rowBase + c;      if (r0 >= NP) r0 = NP - 1;  // tail rows dropped in epilogue
  int r1 = rowBase + 16 + c; if (r1 >= NP) r1 = NP - 1;
  const float* pa0 = counts + (size_t)r0 * OD + g * 8;
  const float* pa1 = counts + (size_t)r1 * OD + g * 8;

  // staging addresses: wave w covers 2 KB of the 8 KB block (2 x 1 KB gll)
  const unsigned short* sbase = bstage + (size_t)wave * 1024 + (size_t)lane * 8;
  unsigned short* dbase0 = &bufB[0][wave * 1024];
  unsigned short* dbase1 = &bufB[1][wave * 1024];

  // ---- prologue: stage t=0 into buf0, load A(t=0) ----
  gll16(sbase, dbase0);
  gll16(sbase + 512, dbase0 + 512);
  float4 a0lo = *(const float4*)(pa0);
  float4 a0hi = *(const float4*)(pa0 + 4);
  float4 a1lo = *(const float4*)(pa1);
  float4 a1hi = *(const float4*)(pa1 + 4);
  asm volatile("s_waitcnt vmcnt(0)" ::: "memory");
  __syncthreads();

  int cur = 0;
  for (int t = 0; t < NT; ++t) {
    const int tn = (t + 1 < NT) ? t + 1 : NT - 1;

    // 1) stage next k-block into the other buffer (2 gll, oldest vm ops)
    const unsigned short* src = sbase + (size_t)tn * 4096;
    unsigned short* dst = (cur == 0) ? dbase1 : dbase0;
    gll16(src, dst);
    gll16(src + 512, dst + 512);
    asm volatile("" ::: "memory");

    // 2) prefetch A for next k-step (4 vm loads, newest)
    const int kon = tn * 32;
    float4 n0lo = *(const float4*)(pa0 + kon);
    float4 n0hi = *(const float4*)(pa0 + kon + 4);
    float4 n1lo = *(const float4*)(pa1 + kon);
    float4 n1hi = *(const float4*)(pa1 + kon + 4);

    // 3) B frags from current buffer: lane-linear ds_read_b128, conflict-free
    const unsigned short* bb = &bufB[cur][0];
    short8 fbh[4], fbl[4];
#pragma unroll
    for (int ct = 0; ct < 4; ++ct) {
      fbh[ct] = *(const short8*)(bb + ct * 512 + lane * 8);
      fbl[ct] = *(const short8*)(bb + 2048 + ct * 512 + lane * 8);
    }

    // 4) pack current A to bf16 (exact: counts are small integers)
    union { unsigned int u[4]; short8 v; } ua0, ua1;
    ua0.u[0] = __builtin_amdgcn_perm(__float_as_uint(a0lo.y), __float_as_uint(a0lo.x), 0x07060302u);
    ua0.u[1] = __builtin_amdgcn_perm(__float_as_uint(a0lo.w), __float_as_uint(a0lo.z), 0x07060302u);
    ua0.u[2] = __builtin_amdgcn_perm(__float_as_uint(a0hi.y), __float_as_uint(a0hi.x), 0x07060302u);
    ua0.u[3] = __builtin_amdgcn_perm(__float_as_uint(a0hi.w), __float_as_uint(a0hi.z), 0x07060302u);
    ua1.u[0] = __builtin_amdgcn_perm(__float_as_uint(a1lo.y), __float_as_uint(a1lo.x), 0x07060302u);
    ua1.u[1] = __builtin_amdgcn_perm(__float_as_uint(a1lo.w), __float_as_uint(a1lo.z), 0x07060302u);
    ua1.u[2] = __builtin_amdgcn_perm(__float_as_uint(a1hi.y), __float_as_uint(a1hi.x), 0x07060302u);
    ua1.u[3] = __builtin_amdgcn_perm(__float_as_uint(a1hi.w), __float_as_uint(a1hi.z), 0x07060302u);

#pragma unroll
    for (int ct = 0; ct < 4; ++ct) {
      acc[0][ct] = __builtin_amdgcn_mfma_f32_16x16x32_bf16(ua0.v, fbh[ct], acc[0][ct], 0, 0, 0);
      acc[1][ct] = __builtin_amdgcn_mfma_f32_16x16x32_bf16(ua1.v, fbh[ct], acc[1][ct], 0, 0, 0);
      acc[0][ct] = __builtin_amdgcn_mfma_f32_16x16x32_bf16(ua0.v, fbl[ct], acc[0][ct], 0, 0, 0);
      acc[1][ct] = __builtin_amdgcn_mfma_f32_16x16x32_bf16(ua1.v, fbl[ct], acc[1][ct], 0, 0, 0);
    }

    // 5) wait ONLY the 2 gll ops (oldest); the 4 A loads stay in flight
    asm volatile("s_waitcnt vmcnt(4)" ::: "memory");
    __builtin_amdgcn_s_barrier();

    a0lo = n0lo; a0hi = n0hi; a1lo = n1lo; a1hi = n1hi;
    cur ^= 1;
  }

  // ---- epilogue: + logw, logsumexp over 64 cols per row, accumulate rows ----
  float lw[4];
#pragma unroll
  for (int ct = 0; ct < 4; ++ct) lw[ct] = logw[ct * 16 + c];

  double lsum = 0.0;
#pragma unroll
  for (int rt = 0; rt < 2; ++rt) {
#pragma unroll
    for (int r = 0; r < 4; ++r) {
      // lane holds cols {ct*16+c}, row = rowBase + rt*16 + g*4 + r
      float v0 = acc[rt][0][r] + lw[0];
      float v1 = acc[rt][1][r] + lw[1];
      float v2 = acc[rt][2][r] + lw[2];
      float v3 = acc[rt][3][r] + lw[3];
      float m = fmaxf(fmaxf(v0, v1), fmaxf(v2, v3));
      m = fmaxf(m, __shfl_xor(m, 1));
      m = fmaxf(m, __shfl_xor(m, 2));
      m = fmaxf(m, __shfl_xor(m, 4));
      m = fmaxf(m, __shfl_xor(m, 8));
      float s = __expf(v0 - m) + __expf(v1 - m) + __expf(v2 - m) + __expf(v3 - m);
      s += __shfl_xor(s, 1);
      s += __shfl_xor(s, 2);
      s += __shfl_xor(s, 4);
      s += __shfl_xor(s, 8);
      float lse = m + __logf(s);
      int row = rowBase + rt * 16 + g * 4 + r;
      if (c == 0 && row < NP) lsum += (double)lse;
    }
  }
  lsum += __shfl_xor(lsum, 16);
  lsum += __shfl_xor(lsum, 32);

  __shared__ double wpart[4];
  if (lane == 0) wpart[wave] = lsum;
  __syncthreads();
  if (tid == 0) partials[blockIdx.x] = wpart[0] + wpart[1] + wpart[2] + wpart[3];
}

__global__ void finalize_kernel(const double* __restrict__ partials,
                                float* __restrict__ out) {
  double s = 0.0;
  for (int i = threadIdx.x; i < NBLOCKS; i += 256) s += partials[i];
  s += __shfl_xor(s, 1);
  s += __shfl_xor(s, 2);
  s += __shfl_xor(s, 4);
  s += __shfl_xor(s, 8);
  s += __shfl_xor(s, 16);
  s += __shfl_xor(s, 32);
  __shared__ double sp[4];
  int w = threadIdx.x >> 6, lane = threadIdx.x & 63;
  if (lane == 0) sp[w] = s;
  __syncthreads();
  if (threadIdx.x == 0) out[0] = (float)(sp[0] + sp[1] + sp[2] + sp[3]);
}

extern "C" void kernel_launch(void* const* d_in, const int* in_sizes, int n_in,
                              void* d_out, int out_size, void* d_ws, size_t ws_size,
                              hipStream_t stream) {
  const float* counts = (const float*)d_in[0];
  const float* otu    = (const float*)d_in[1];
  const float* comm   = (const float*)d_in[2];
  float* out = (float*)d_out;
  char* ws = (char*)d_ws;

  float* logw          = (float*)(ws + WS_LOGW);
  double* partials     = (double*)(ws + WS_PARTIALS);
  unsigned short* bst  = (unsigned short*)(ws + WS_BSTAGE);

  prep_kernel<<<KC + 1, 256, 0, stream>>>(otu, comm, bst, logw);
  ll_kernel<<<NBLOCKS, 256, 0, stream>>>(counts, bst, logw, partials);
  finalize_kernel<<<1, 256, 0, stream>>>(partials, out);
}